// Round 9
// baseline (121.736 us; speedup 1.0000x reference)
//
#include <hip/hip_runtime.h>
#include <math.h>

// Problem constants (fixed by setup_inputs)
#define BSZ    2
#define LFULL  4096
#define MLEN   2048      // M = hidden_states.shape[1]
#define DMODEL 2048
#define CLIP_EPS 1e-4f
#define CCH    256       // number of chunks
#define TCH    8         // chunk length; CCH*TCH == MLEN

typedef float f4 __attribute__((ext_vector_type(4)));

// ---------------------------------------------------------------------------
// D1: mega_front — column blocks; prep + local scan + cross-chunk scan.
// Identical to the verified R7 mega through phase D; epilogue replaced by
// exports: G (carry-in per chunk/d4, 4.2 MB) + per-position params
// (wA/eA/cde/Ls/Le, bx==0 lanes only).
// grid: (DMODEL/16, BSZ) = (128, 2) = 256 blocks x 1024 threads (1/CU).
// ---------------------------------------------------------------------------
__global__ __launch_bounds__(1024, 4) void mega_front(
    const float* __restrict__ hid, const int* __restrict__ bmask_raw,
    const float* __restrict__ bprob,
    int* __restrict__ Ls, int* __restrict__ Le,
    float* __restrict__ wA, float* __restrict__ eA,
    float* __restrict__ cde, float* __restrict__ G)
{
  const int tid = threadIdx.x;
  const int j   = tid & 3;          // f4 lane within the 16-float strip
  const int c   = tid >> 2;         // chunk [0, 256)
  const int bx  = blockIdx.x;       // strip [0, 128)
  const int b   = blockIdx.y;       // batch

  __shared__ int   s_sel[MLEN];     // 8 KB
  __shared__ float s_P[CCH];        // 1 KB
  __shared__ f4    s_S[CCH][4];     // 16 KB
  __shared__ int   s_wtot[16];
  __shared__ int   s_mode, s_ntrue;

  // ---- phase A: issue this block's hid loads; keep-alive pins them ----
  const int d4 = bx * 4 + j;        // f4 column index [0, 512)
  const int o  = b * MLEN + c * TCH;
  const f4* xp = (const f4*)hid + ((size_t)o * DMODEL >> 2) + d4;
  f4 xr[TCH];
  #pragma unroll
  for (int t = 0; t < TCH; ++t) xr[t] = xp[(size_t)t * (DMODEL / 4)];
  #pragma unroll
  for (int t = 0; t < TCH; ++t) asm volatile("" : "+v"(xr[t]));

  // ---- phase B: redundant prep, all 1024 threads (4 positions each) ----
  if (tid == 0) {
    unsigned w0 = ((const unsigned*)bmask_raw)[0];
    s_mode = (w0 <= 1u) ? 1 : 0;    // 1: int32 per element, 0: uint8
  }
  __syncthreads();
  const int mode = s_mode;
  const unsigned char* bmask_u8 = (const unsigned char*)bmask_raw;

  const int PER  = LFULL / 1024;    // 4 positions per thread
  const int base = tid * PER;

  int cnt = 0;
  #pragma unroll
  for (int i = 0; i < PER; ++i) {
    const int L = base + i;
    const int v = mode ? (bmask_raw[b * LFULL + L] != 0)
                       : (bmask_u8[b * LFULL + L] != 0);
    cnt += v;
  }

  // two-level exclusive prefix over 1024 per-thread counts
  const int lane = tid & 63, wv = tid >> 6;
  int incl = cnt;
  #pragma unroll
  for (int off = 1; off < 64; off <<= 1) {
    const int v = __shfl_up(incl, off, 64);
    if (lane >= off) incl += v;
  }
  if (lane == 63) s_wtot[wv] = incl;
  __syncthreads();
  if (tid == 0) {
    int run = 0;
    #pragma unroll
    for (int w = 0; w < 16; ++w) { const int t = s_wtot[w]; s_wtot[w] = run; run += t; }
    s_ntrue = run;
  }
  __syncthreads();
  const int excl  = (incl - cnt) + s_wtot[wv];
  const int ntrue = s_ntrue;

  // fill sel: boundary positions (rank) then non-boundary (ntrue + false-rank)
  {
    int trun = excl;
    #pragma unroll
    for (int i = 0; i < PER; ++i) {
      const int L = base + i;
      const int v = mode ? (bmask_raw[b * LFULL + L] != 0)
                         : (bmask_u8[b * LFULL + L] != 0);
      if (v) {
        if (trun < MLEN) s_sel[trun] = L;
        ++trun;
      } else {
        const int f = L - trun;          // falses strictly before L
        const int slot = ntrue + f;
        if (slot < MLEN) s_sel[slot] = L;
      }
    }
  }
  __syncthreads();

  // own-chunk params (4 j-lanes redundant); bit-identical formulas.
  float w[TCH], e[TCH], cd[TCH];
  {
    float run = 1.0f;
    #pragma unroll
    for (int t = 0; t < TCH; ++t) {
      const int L = s_sel[c * TCH + t];
      float p = bprob[((size_t)b * LFULL + L) * 2 + 1];
      p = fminf(fmaxf(p, CLIP_EPS), 1.0f - CLIP_EPS);
      const float dt = -log1pf(-p);      // log(1/(1-p))
      w[t] = p / dt;
      e[t] = 1.0f - p;                   // exp(-dt) exactly
      run *= e[t];
      cd[t] = run;
    }
  }

  // ---- phase C: local chunk scan in registers; publish S, P ----
  f4 st = {0.f, 0.f, 0.f, 0.f};
  #pragma unroll
  for (int t = 0; t < TCH; ++t) {
    const f4 x = xr[t];
    st.x = fmaf(e[t], st.x, w[t] * x.x);
    st.y = fmaf(e[t], st.y, w[t] * x.y);
    st.z = fmaf(e[t], st.z, w[t] * x.z);
    st.w = fmaf(e[t], st.w, w[t] * x.w);
  }
  s_S[c][j] = st;
  if (j == 0) s_P[c] = cd[TCH - 1];      // chunk product
  __syncthreads();

  // ---- phase D: Hillis-Steele over 256 chunks (identical to k25 math) ----
  for (int dstep = 1; dstep < CCH; dstep <<= 1) {
    const float pc = s_P[c];
    float pd = 1.0f;
    f4 sd = {0.f, 0.f, 0.f, 0.f};
    if (c >= dstep) { pd = s_P[c - dstep]; sd = s_S[c - dstep][j]; }
    __syncthreads();
    if (c >= dstep) {
      f4 cur = s_S[c][j];
      cur.x = fmaf(pc, sd.x, cur.x);
      cur.y = fmaf(pc, sd.y, cur.y);
      cur.z = fmaf(pc, sd.z, cur.z);
      cur.w = fmaf(pc, sd.w, cur.w);
      s_S[c][j] = cur;
      if (j == 0) s_P[c] = pc * pd;
    }
    __syncthreads();
  }

  // exclusive shift: carry-in for chunk c is inclusive scan at c-1
  f4 H = {0.f, 0.f, 0.f, 0.f};
  if (c > 0) H = s_S[c - 1][j];

  // ---- exports ----
  // G[b][c][d4]: every thread writes its own slice (disjoint).
  ((f4*)G)[((size_t)(b * CCH + c) * DMODEL >> 2) + d4] = H;

  // small params: one block per batch (bx==0), j==0 lanes only.
  if (bx == 0 && j == 0) {
    const int nb = (ntrue < MLEN) ? ntrue : MLEN;
    #pragma unroll
    for (int t = 0; t < TCH; ++t) {
      const int g = c * TCH + t;
      wA[b * MLEN + g]  = w[t];
      eA[b * MLEN + g]  = e[t];
      cde[b * MLEN + g] = cd[t];
      int ls, le;
      if (nb == 0) {
        ls = (g == 0) ? 0 : LFULL;
        le = (g == 0) ? LFULL : LFULL;
      } else if (g < nb) {
        ls = (g == 0) ? 0 : s_sel[g];
        le = (g == nb - 1) ? LFULL : s_sel[g + 1];
      } else {
        ls = LFULL; le = LFULL;          // empty
      }
      Ls[b * MLEN + g] = ls;
      Le[b * MLEN + g] = le;
    }
  }
}

// ---------------------------------------------------------------------------
// D2: k3_out — verified R0 kernel, verbatim. Row blocks, fully coalesced:
// redo local scan from hid (L3-hot after D1), y = st + cde*G, NT scatter.
// grid: (2, CCH, BSZ) = 1024 blocks x 256 threads
// ---------------------------------------------------------------------------
__global__ __launch_bounds__(256) void k3_out(
    const float* __restrict__ hid, const float* __restrict__ wA,
    const float* __restrict__ eA, const float* __restrict__ cde,
    const float* __restrict__ G,
    const int* __restrict__ Ls, const int* __restrict__ Le,
    float* __restrict__ out)
{
  const int tid = threadIdx.x;
  const int c = blockIdx.y;
  const int b = blockIdx.z;

  __shared__ float s_w[TCH], s_e[TCH], s_c[TCH];
  __shared__ int   s_ls[TCH], s_le[TCH];
  const int o = b * MLEN + c * TCH;
  if (tid < TCH)          { s_w[tid] = wA[o + tid];  s_ls[tid] = Ls[o + tid]; }
  else if (tid < 2 * TCH) { const int t = tid - TCH;     s_e[t] = eA[o + t]; s_le[t] = Le[o + t]; }
  else if (tid < 3 * TCH) { const int t = tid - 2 * TCH; s_c[t] = cde[o + t]; }
  __syncthreads();

  const int d4 = blockIdx.x * 256 + tid;

  const f4 H = ((const f4*)G)[((size_t)(b * CCH + c) * DMODEL >> 2) + d4];

  const f4* xp = (const f4*)hid + ((size_t)(b * MLEN + c * TCH) * DMODEL >> 2) + d4;
  f4*       op = (f4*)out + ((size_t)b * LFULL * DMODEL >> 2) + d4;

  f4 st = {0.f, 0.f, 0.f, 0.f};
  #pragma unroll
  for (int t = 0; t < TCH; ++t) {
    const f4 x = xp[(size_t)t * (DMODEL / 4)];
    const float w = s_w[t], e = s_e[t], cd = s_c[t];
    st.x = fmaf(e, st.x, w * x.x);
    st.y = fmaf(e, st.y, w * x.y);
    st.z = fmaf(e, st.z, w * x.z);
    st.w = fmaf(e, st.w, w * x.w);
    f4 y;
    y.x = fmaf(cd, H.x, st.x);
    y.y = fmaf(cd, H.y, st.y);
    y.z = fmaf(cd, H.z, st.z);
    y.w = fmaf(cd, H.w, st.w);
    const int ls = s_ls[t], le = s_le[t];
    for (int L = ls; L < le; ++L) {
      __builtin_nontemporal_store(y, op + (size_t)L * (DMODEL / 4));
    }
  }
}

// ---------------------------------------------------------------------------
extern "C" void kernel_launch(void* const* d_in, const int* in_sizes, int n_in,
                              void* d_out, int out_size, void* d_ws, size_t ws_size,
                              hipStream_t stream) {
  const float* hid   = (const float*)d_in[0];   // (2, 2048, 2048) fp32
  const int*   bmask = (const int*)d_in[1];     // (2, 4096) bool (layout sniffed)
  const float* bprob = (const float*)d_in[2];   // (2, 4096, 2) fp32
  float*       out   = (float*)d_out;           // (2, 4096, 2048) fp32

  char* ws = (char*)d_ws;
  const size_t SZI = (size_t)BSZ * MLEN * sizeof(int);    // 16 KB
  const size_t SZF = (size_t)BSZ * MLEN * sizeof(float);  // 16 KB
  int*   Ls  = (int*)(ws);
  int*   Le  = (int*)(ws + SZI);
  float* wA  = (float*)(ws + 2 * SZI);
  float* eA  = (float*)(ws + 2 * SZI + SZF);
  float* cde = (float*)(ws + 2 * SZI + 2 * SZF);
  float* G   = (float*)(ws + 2 * SZI + 3 * SZF + 4096);   // 4.2 MB

  mega_front<<<dim3(DMODEL / 16, BSZ), dim3(1024), 0, stream>>>(
      hid, bmask, bprob, Ls, Le, wA, eA, cde, G);

  k3_out<<<dim3(2, CCH, BSZ), dim3(256), 0, stream>>>(
      hid, wA, eA, cde, G, Ls, Le, out);
}

// Round 10
// 118.146 us; speedup vs baseline: 1.0304x; 1.0304x over previous
//
#include <hip/hip_runtime.h>
#include <math.h>

// Problem constants (fixed by setup_inputs)
#define BSZ    2
#define LFULL  4096
#define MLEN   2048      // M = hidden_states.shape[1]
#define DMODEL 2048
#define CLIP_EPS 1e-4f
#define CCH    256       // number of chunks
#define TCH    8         // chunk length; CCH*TCH == MLEN
#define HCH    128       // chunks per half (two-level scan)

typedef float f4 __attribute__((ext_vector_type(4)));

// ---------------------------------------------------------------------------
// D1: front — 1024 threads = 128 chunks (cl) x 8 j-lanes. Each wave's 8
// consecutive j-lanes cover a FULL 128-B line per row (vs 64-B in R7/R9),
// with the same 32 pinned VGPRs (one f4 column x 8 positions). Half-scan
// (7-step Hillis-Steele) per block; halves stitched algebraically in D2.
// Exports: Gpart (4.2 MB), E carry (16 KB), cumP1 (1 KB), k3 params (80 KB).
// grid: (64 strips, 2 halves, BSZ) = 256 blocks (1/CU).
// ---------------------------------------------------------------------------
__global__ __launch_bounds__(1024, 4) void front(
    const float* __restrict__ hid, const int* __restrict__ bmask_raw,
    const float* __restrict__ bprob,
    int* __restrict__ Ls, int* __restrict__ Le,
    float* __restrict__ wA, float* __restrict__ eA,
    float* __restrict__ cde, float* __restrict__ Gp,
    float* __restrict__ Ecar, float* __restrict__ cumP1)
{
  const int tid = threadIdx.x;
  const int j   = tid & 7;          // f4 lane within the 32-float strip
  const int cl  = tid >> 3;         // local chunk [0, 128)
  const int s   = blockIdx.x;       // strip [0, 64)
  const int h   = blockIdx.y;       // half [0, 2)
  const int b   = blockIdx.z;       // batch
  const int c   = h * HCH + cl;     // global chunk

  __shared__ int   s_sel[MLEN];     // 8 KB
  __shared__ float s_P[HCH];        // 0.5 KB
  __shared__ f4    s_S[HCH][9];     // 18.4 KB (col 8 = pad -> bank spread)
  __shared__ int   s_wtot[16];
  __shared__ int   s_mode, s_ntrue;

  // ---- phase A: issue hid loads (128-B line granular); pin them ----
  const int d4 = s * 8 + j;         // f4 column [0, 512)
  const int o  = b * MLEN + c * TCH;
  const f4* xp = (const f4*)hid + ((size_t)o * DMODEL >> 2) + d4;
  f4 xr[TCH];
  #pragma unroll
  for (int t = 0; t < TCH; ++t) xr[t] = xp[(size_t)t * (DMODEL / 4)];
  #pragma unroll
  for (int t = 0; t < TCH; ++t) asm volatile("" : "+v"(xr[t]));

  // ---- phase B: redundant prep, all 1024 threads (4 positions each) ----
  if (tid == 0) {
    unsigned w0 = ((const unsigned*)bmask_raw)[0];
    s_mode = (w0 <= 1u) ? 1 : 0;    // 1: int32 per element, 0: uint8
  }
  __syncthreads();
  const int mode = s_mode;
  const unsigned char* bmask_u8 = (const unsigned char*)bmask_raw;

  const int PER  = LFULL / 1024;    // 4 positions per thread
  const int base = tid * PER;

  int cnt = 0;
  #pragma unroll
  for (int i = 0; i < PER; ++i) {
    const int L = base + i;
    const int v = mode ? (bmask_raw[b * LFULL + L] != 0)
                       : (bmask_u8[b * LFULL + L] != 0);
    cnt += v;
  }

  const int lane = tid & 63, wv = tid >> 6;
  int incl = cnt;
  #pragma unroll
  for (int off = 1; off < 64; off <<= 1) {
    const int v = __shfl_up(incl, off, 64);
    if (lane >= off) incl += v;
  }
  if (lane == 63) s_wtot[wv] = incl;
  __syncthreads();
  if (tid == 0) {
    int run = 0;
    #pragma unroll
    for (int w = 0; w < 16; ++w) { const int t = s_wtot[w]; s_wtot[w] = run; run += t; }
    s_ntrue = run;
  }
  __syncthreads();
  const int excl  = (incl - cnt) + s_wtot[wv];
  const int ntrue = s_ntrue;

  {
    int trun = excl;
    #pragma unroll
    for (int i = 0; i < PER; ++i) {
      const int L = base + i;
      const int v = mode ? (bmask_raw[b * LFULL + L] != 0)
                         : (bmask_u8[b * LFULL + L] != 0);
      if (v) {
        if (trun < MLEN) s_sel[trun] = L;
        ++trun;
      } else {
        const int f = L - trun;          // falses strictly before L
        const int slot = ntrue + f;
        if (slot < MLEN) s_sel[slot] = L;
      }
    }
  }
  __syncthreads();

  // own-chunk params (8 j-lanes redundant); bit-identical formulas.
  float w[TCH], e[TCH], cd[TCH];
  {
    float run = 1.0f;
    #pragma unroll
    for (int t = 0; t < TCH; ++t) {
      const int L = s_sel[c * TCH + t];
      float p = bprob[((size_t)b * LFULL + L) * 2 + 1];
      p = fminf(fmaxf(p, CLIP_EPS), 1.0f - CLIP_EPS);
      const float dt = -log1pf(-p);      // log(1/(1-p))
      w[t] = p / dt;
      e[t] = 1.0f - p;                   // exp(-dt) exactly
      run *= e[t];
      cd[t] = run;
    }
  }

  // ---- phase C: local chunk scan; publish S, P ----
  f4 st = {0.f, 0.f, 0.f, 0.f};
  #pragma unroll
  for (int t = 0; t < TCH; ++t) {
    const f4 x = xr[t];
    st.x = fmaf(e[t], st.x, w[t] * x.x);
    st.y = fmaf(e[t], st.y, w[t] * x.y);
    st.z = fmaf(e[t], st.z, w[t] * x.z);
    st.w = fmaf(e[t], st.w, w[t] * x.w);
  }
  s_S[cl][j] = st;
  if (j == 0) s_P[cl] = cd[TCH - 1];     // chunk product
  __syncthreads();

  // ---- phase D: 7-step Hillis-Steele over this half's 128 chunks ----
  for (int dstep = 1; dstep < HCH; dstep <<= 1) {
    const float pc = s_P[cl];
    float pd = 1.0f;
    f4 sd = {0.f, 0.f, 0.f, 0.f};
    if (cl >= dstep) { pd = s_P[cl - dstep]; sd = s_S[cl - dstep][j]; }
    __syncthreads();
    if (cl >= dstep) {
      f4 cur = s_S[cl][j];
      cur.x = fmaf(pc, sd.x, cur.x);
      cur.y = fmaf(pc, sd.y, cur.y);
      cur.z = fmaf(pc, sd.z, cur.z);
      cur.w = fmaf(pc, sd.w, cur.w);
      s_S[cl][j] = cur;
      if (j == 0) s_P[cl] = pc * pd;
    }
    __syncthreads();
  }

  // ---- exports ----
  // partial exclusive carry within the half (128-B granular writes)
  f4 Hx = {0.f, 0.f, 0.f, 0.f};
  if (cl > 0) Hx = s_S[cl - 1][j];
  ((f4*)Gp)[((size_t)(b * CCH + c) * DMODEL >> 2) + d4] = Hx;

  // E: half-0 inclusive state at chunk 127 (state entering chunk 128)
  if (h == 0 && cl == HCH - 1)
    ((f4*)Ecar)[(b * (DMODEL / 4)) + d4] = s_S[HCH - 1][j];

  // cumP1[cl] = prod of chunk products over [128, 128+cl)
  if (h == 1 && s == 0 && j == 0)
    cumP1[b * HCH + cl] = (cl == 0) ? 1.0f : s_P[cl - 1];

  // per-position params for D2 (one strip's j==0 lanes per half)
  if (s == 0 && j == 0) {
    const int nb = (ntrue < MLEN) ? ntrue : MLEN;
    #pragma unroll
    for (int t = 0; t < TCH; ++t) {
      const int g = c * TCH + t;
      wA[b * MLEN + g]  = w[t];
      eA[b * MLEN + g]  = e[t];
      cde[b * MLEN + g] = cd[t];
      int ls, le;
      if (nb == 0) {
        ls = (g == 0) ? 0 : LFULL;
        le = (g == 0) ? LFULL : LFULL;
      } else if (g < nb) {
        ls = (g == 0) ? 0 : s_sel[g];
        le = (g == nb - 1) ? LFULL : s_sel[g + 1];
      } else {
        ls = LFULL; le = LFULL;          // empty
      }
      Ls[b * MLEN + g] = ls;
      Le[b * MLEN + g] = le;
    }
  }
}

// ---------------------------------------------------------------------------
// D2: k3_out — verified row-coalesced writer + half-stitch fixup:
//   G[c] = Gpart[c]            (c < 128)
//        = Gpart[c] + cumP1[c-128] * E   (c >= 128)
// grid: (2, CCH, BSZ) = 1024 blocks x 256 threads
// ---------------------------------------------------------------------------
__global__ __launch_bounds__(256) void k3_out(
    const float* __restrict__ hid, const float* __restrict__ wA,
    const float* __restrict__ eA, const float* __restrict__ cde,
    const float* __restrict__ Gp, const float* __restrict__ Ecar,
    const float* __restrict__ cumP1,
    const int* __restrict__ Ls, const int* __restrict__ Le,
    float* __restrict__ out)
{
  const int tid = threadIdx.x;
  const int c = blockIdx.y;
  const int b = blockIdx.z;

  __shared__ float s_w[TCH], s_e[TCH], s_c[TCH];
  __shared__ int   s_ls[TCH], s_le[TCH];
  const int o = b * MLEN + c * TCH;
  if (tid < TCH)          { s_w[tid] = wA[o + tid];  s_ls[tid] = Ls[o + tid]; }
  else if (tid < 2 * TCH) { const int t = tid - TCH;     s_e[t] = eA[o + t]; s_le[t] = Le[o + t]; }
  else if (tid < 3 * TCH) { const int t = tid - 2 * TCH; s_c[t] = cde[o + t]; }
  __syncthreads();

  const int d4 = blockIdx.x * 256 + tid;

  f4 H = ((const f4*)Gp)[((size_t)(b * CCH + c) * DMODEL >> 2) + d4];
  if (c >= HCH) {                        // uniform per block
    const float cp = cumP1[b * HCH + (c - HCH)];
    const f4 Ev = ((const f4*)Ecar)[(b * (DMODEL / 4)) + d4];
    H.x = fmaf(cp, Ev.x, H.x);
    H.y = fmaf(cp, Ev.y, H.y);
    H.z = fmaf(cp, Ev.z, H.z);
    H.w = fmaf(cp, Ev.w, H.w);
  }

  const f4* xp = (const f4*)hid + ((size_t)(b * MLEN + c * TCH) * DMODEL >> 2) + d4;
  f4*       op = (f4*)out + ((size_t)b * LFULL * DMODEL >> 2) + d4;

  f4 st = {0.f, 0.f, 0.f, 0.f};
  #pragma unroll
  for (int t = 0; t < TCH; ++t) {
    const f4 x = xp[(size_t)t * (DMODEL / 4)];
    const float w = s_w[t], e = s_e[t], cd = s_c[t];
    st.x = fmaf(e, st.x, w * x.x);
    st.y = fmaf(e, st.y, w * x.y);
    st.z = fmaf(e, st.z, w * x.z);
    st.w = fmaf(e, st.w, w * x.w);
    f4 y;
    y.x = fmaf(cd, H.x, st.x);
    y.y = fmaf(cd, H.y, st.y);
    y.z = fmaf(cd, H.z, st.z);
    y.w = fmaf(cd, H.w, st.w);
    const int ls = s_ls[t], le = s_le[t];
    for (int L = ls; L < le; ++L) {
      __builtin_nontemporal_store(y, op + (size_t)L * (DMODEL / 4));
    }
  }
}

// ---------------------------------------------------------------------------
extern "C" void kernel_launch(void* const* d_in, const int* in_sizes, int n_in,
                              void* d_out, int out_size, void* d_ws, size_t ws_size,
                              hipStream_t stream) {
  const float* hid   = (const float*)d_in[0];   // (2, 2048, 2048) fp32
  const int*   bmask = (const int*)d_in[1];     // (2, 4096) bool (layout sniffed)
  const float* bprob = (const float*)d_in[2];   // (2, 4096, 2) fp32
  float*       out   = (float*)d_out;           // (2, 4096, 2048) fp32

  char* ws = (char*)d_ws;
  const size_t SZI = (size_t)BSZ * MLEN * sizeof(int);    // 16 KB
  const size_t SZF = (size_t)BSZ * MLEN * sizeof(float);  // 16 KB
  int*   Ls    = (int*)(ws);
  int*   Le    = (int*)(ws + SZI);
  float* wA    = (float*)(ws + 2 * SZI);
  float* eA    = (float*)(ws + 2 * SZI + SZF);
  float* cde   = (float*)(ws + 2 * SZI + 2 * SZF);
  float* cumP  = (float*)(ws + 2 * SZI + 3 * SZF);          // 1 KB
  float* Ecar  = (float*)(ws + 2 * SZI + 3 * SZF + 1024);   // 16 KB
  float* Gp    = (float*)(ws + 2 * SZI + 3 * SZF + 1024 + 16384 + 2048); // 4.2 MB, 16B-aligned

  front<<<dim3(DMODEL / 32, 2, BSZ), dim3(1024), 0, stream>>>(
      hid, bmask, bprob, Ls, Le, wA, eA, cde, Gp, Ecar, cumP);

  k3_out<<<dim3(2, CCH, BSZ), dim3(256), 0, stream>>>(
      hid, wA, eA, cde, Gp, Ecar, cumP, Ls, Le, out);
}

// Round 11
// 111.469 us; speedup vs baseline: 1.0921x; 1.0599x over previous
//
#include <hip/hip_runtime.h>
#include <math.h>

// Problem constants (fixed by setup_inputs)
#define BSZ    2
#define LFULL  4096
#define MLEN   2048      // M = hidden_states.shape[1]
#define DMODEL 2048
#define CLIP_EPS 1e-4f
#define CCH    256       // number of chunks
#define TCH    8         // chunk length; CCH*TCH == MLEN

typedef float f4 __attribute__((ext_vector_type(4)));

// ---------------------------------------------------------------------------
// MEGA v2b: R7's verified single-dispatch kernel with EXACTLY ONE change:
// plain (cached) stores for `out` instead of __builtin_nontemporal_store.
// A/B rationale: R5/R7/R10 (three different decompositions) all plateau at
// a ~31-33 us controllable slice; the one shared factor never tested is the
// NT store path on the dominant 67 MB write. Plain full-line stores show no
// RFO over-fetch (WRITE_SIZE was exactly 65536 KB), and nothing is read
// after phase E, so cache pollution is harmless.
//
// grid: (DMODEL/16, BSZ) = (128, 2) = 256 blocks x 1024 threads.
// All arithmetic bit-identical to the verified pipeline (absmax 0.03125).
// ---------------------------------------------------------------------------
__global__ __launch_bounds__(1024, 2) void mega(
    const float* __restrict__ hid, const int* __restrict__ bmask_raw,
    const float* __restrict__ bprob, float* __restrict__ out)
{
  const int tid = threadIdx.x;
  const int j   = tid & 3;          // f4 lane within the 16-float strip
  const int c   = tid >> 2;         // chunk [0, 256)
  const int bx  = blockIdx.x;       // strip [0, 128)
  const int b   = blockIdx.y;       // batch

  __shared__ int   s_sel[MLEN];     // 8 KB, alive through the epilogue
  __shared__ float s_P[CCH];        // 1 KB
  __shared__ f4    s_S[CCH][4];     // 16 KB
  __shared__ int   s_wtot[16];      // per-wave counts -> exclusive offsets
  __shared__ int   s_mode, s_ntrue;

  // ---- phase A: issue this block's hid loads; keep-alive pins them ----
  const int d4 = bx * 4 + j;        // f4 column index [0, 512)
  const int o  = b * MLEN + c * TCH;
  const f4* xp = (const f4*)hid + ((size_t)o * DMODEL >> 2) + d4;
  f4 xr[TCH];
  #pragma unroll
  for (int t = 0; t < TCH; ++t) xr[t] = xp[(size_t)t * (DMODEL / 4)];
  #pragma unroll
  for (int t = 0; t < TCH; ++t) asm volatile("" : "+v"(xr[t]));

  // ---- phase B: redundant prep, all 1024 threads (4 positions each) ----
  if (tid == 0) {
    unsigned w0 = ((const unsigned*)bmask_raw)[0];
    s_mode = (w0 <= 1u) ? 1 : 0;    // 1: int32 per element, 0: uint8
  }
  __syncthreads();
  const int mode = s_mode;
  const unsigned char* bmask_u8 = (const unsigned char*)bmask_raw;

  const int PER  = LFULL / 1024;    // 4 positions per thread
  const int base = tid * PER;

  int cnt = 0;
  {
    #pragma unroll
    for (int i = 0; i < PER; ++i) {
      const int L = base + i;
      const int v = mode ? (bmask_raw[b * LFULL + L] != 0)
                         : (bmask_u8[b * LFULL + L] != 0);
      cnt += v;
    }
  }

  // two-level exclusive prefix over 1024 per-thread counts
  const int lane = tid & 63, wv = tid >> 6;
  int incl = cnt;
  #pragma unroll
  for (int off = 1; off < 64; off <<= 1) {
    const int v = __shfl_up(incl, off, 64);
    if (lane >= off) incl += v;
  }
  if (lane == 63) s_wtot[wv] = incl;     // wave totals
  __syncthreads();
  if (tid == 0) {
    int run = 0;
    #pragma unroll
    for (int w = 0; w < 16; ++w) { const int t = s_wtot[w]; s_wtot[w] = run; run += t; }
    s_ntrue = run;
  }
  __syncthreads();
  const int excl  = (incl - cnt) + s_wtot[wv];
  const int ntrue = s_ntrue;

  // fill sel: boundary positions (rank) then non-boundary (ntrue + false-rank)
  {
    int trun = excl;
    #pragma unroll
    for (int i = 0; i < PER; ++i) {
      const int L = base + i;
      const int v = mode ? (bmask_raw[b * LFULL + L] != 0)
                         : (bmask_u8[b * LFULL + L] != 0);
      if (v) {
        if (trun < MLEN) s_sel[trun] = L;
        ++trun;
      } else {
        const int f = L - trun;          // falses strictly before L
        const int slot = ntrue + f;
        if (slot < MLEN) s_sel[slot] = L;
      }
    }
  }
  __syncthreads();

  // own-chunk params to registers (4 j-lanes compute redundantly);
  // bit-identical formulas: w = p/dt, e = 1-p, cde = running product.
  float w[TCH], e[TCH], cd[TCH];
  {
    float run = 1.0f;
    #pragma unroll
    for (int t = 0; t < TCH; ++t) {
      const int L = s_sel[c * TCH + t];
      float p = bprob[((size_t)b * LFULL + L) * 2 + 1];
      p = fminf(fmaxf(p, CLIP_EPS), 1.0f - CLIP_EPS);
      const float dt = -log1pf(-p);      // log(1/(1-p))
      w[t] = p / dt;
      e[t] = 1.0f - p;                   // exp(-dt) exactly
      run *= e[t];
      cd[t] = run;
    }
  }

  // ---- phase C: local chunk scan in registers; publish S, P ----
  f4 st = {0.f, 0.f, 0.f, 0.f};
  #pragma unroll
  for (int t = 0; t < TCH; ++t) {
    const f4 x = xr[t];
    st.x = fmaf(e[t], st.x, w[t] * x.x);
    st.y = fmaf(e[t], st.y, w[t] * x.y);
    st.z = fmaf(e[t], st.z, w[t] * x.z);
    st.w = fmaf(e[t], st.w, w[t] * x.w);
    xr[t] = st;                          // running local state at position t
  }
  s_S[c][j] = st;
  if (j == 0) s_P[c] = cd[TCH - 1];      // chunk product
  __syncthreads();

  // ---- phase D: Hillis-Steele over 256 chunks (identical to k25 math) ----
  for (int dstep = 1; dstep < CCH; dstep <<= 1) {
    const float pc = s_P[c];
    float pd = 1.0f;
    f4 sd = {0.f, 0.f, 0.f, 0.f};
    if (c >= dstep) { pd = s_P[c - dstep]; sd = s_S[c - dstep][j]; }
    __syncthreads();
    if (c >= dstep) {
      f4 cur = s_S[c][j];
      cur.x = fmaf(pc, sd.x, cur.x);
      cur.y = fmaf(pc, sd.y, cur.y);
      cur.z = fmaf(pc, sd.z, cur.z);
      cur.w = fmaf(pc, sd.w, cur.w);
      s_S[c][j] = cur;
      if (j == 0) s_P[c] = pc * pd;
    }
    __syncthreads();
  }

  // exclusive shift: carry-in for chunk c is inclusive scan at c-1
  f4 H = {0.f, 0.f, 0.f, 0.f};
  if (c > 0) H = s_S[c - 1][j];

  // ---- phase E: y = xr + cde*H, PLAIN stores to rows [ls, le) ----
  const int nb = (ntrue < MLEN) ? ntrue : MLEN;
  f4* op = (f4*)out + ((size_t)b * LFULL * DMODEL >> 2) + d4;
  #pragma unroll
  for (int t = 0; t < TCH; ++t) {
    const int g = c * TCH + t;           // global selected index [0, MLEN)
    int ls, le;
    if (nb == 0) {
      ls = (g == 0) ? 0 : LFULL;
      le = (g == 0) ? LFULL : LFULL;
    } else if (g < nb) {
      ls = (g == 0) ? 0 : s_sel[g];
      le = (g == nb - 1) ? LFULL : s_sel[g + 1];
    } else {
      ls = LFULL; le = LFULL;            // empty
    }
    f4 y;
    y.x = fmaf(cd[t], H.x, xr[t].x);
    y.y = fmaf(cd[t], H.y, xr[t].y);
    y.z = fmaf(cd[t], H.z, xr[t].z);
    y.w = fmaf(cd[t], H.w, xr[t].w);
    for (int L = ls; L < le; ++L) {
      op[(size_t)L * (DMODEL / 4)] = y;  // plain cached store (A/B vs NT)
    }
  }
}

// ---------------------------------------------------------------------------
extern "C" void kernel_launch(void* const* d_in, const int* in_sizes, int n_in,
                              void* d_out, int out_size, void* d_ws, size_t ws_size,
                              hipStream_t stream) {
  const float* hid   = (const float*)d_in[0];   // (2, 2048, 2048) fp32
  const int*   bmask = (const int*)d_in[1];     // (2, 4096) bool (layout sniffed)
  const float* bprob = (const float*)d_in[2];   // (2, 4096, 2) fp32
  float*       out   = (float*)d_out;           // (2, 4096, 2048) fp32
  (void)d_ws; (void)ws_size;

  mega<<<dim3(DMODEL / 16, BSZ), dim3(1024), 0, stream>>>(hid, bmask, bprob, out);
}

// Round 12
// 107.484 us; speedup vs baseline: 1.1326x; 1.0371x over previous
//
#include <hip/hip_runtime.h>
#include <math.h>

// Problem constants (fixed by setup_inputs)
#define BSZ    2
#define LFULL  4096
#define MLEN   2048      // M = hidden_states.shape[1]
#define DMODEL 2048
#define CLIP_EPS 1e-4f
#define CCH    256       // number of chunks
#define TCH    8         // chunk length; CCH*TCH == MLEN

typedef float f4 __attribute__((ext_vector_type(4)));

// ---------------------------------------------------------------------------
// MEGA v2c: R11's verified kernel (plain stores) + ONE change:
// bijective XCD-pair swizzle of blockIdx.x. Default round-robin puts
// adjacent 64-B strips (which share a 128-B line of hid/out) on DIFFERENT
// XCDs: reads get cross-die L3 hits instead of local L2 hits; writes leave
// half-dirty lines in two L2s (partial-line writebacks). Swizzle
// bx = (bid%8)*16 + bid/8 gives each XCD 16 consecutive strips, so both
// halves of every line live in one L2 (merged reads + full-line writebacks).
// Work permutation only -> absmax stays exactly 0.03125.
//
// grid: (DMODEL/16, BSZ) = (128, 2) = 256 blocks x 1024 threads.
// ---------------------------------------------------------------------------
__global__ __launch_bounds__(1024, 2) void mega(
    const float* __restrict__ hid, const int* __restrict__ bmask_raw,
    const float* __restrict__ bprob, float* __restrict__ out)
{
  const int tid = threadIdx.x;
  const int j   = tid & 3;          // f4 lane within the 16-float strip
  const int c   = tid >> 2;         // chunk [0, 256)
  const int bid = blockIdx.x;       // raw [0, 128)
  const int bx  = (bid & 7) * 16 + (bid >> 3);  // XCD-chunked strip [0,128)
  const int b   = blockIdx.y;       // batch

  __shared__ int   s_sel[MLEN];     // 8 KB, alive through the epilogue
  __shared__ float s_P[CCH];        // 1 KB
  __shared__ f4    s_S[CCH][4];     // 16 KB
  __shared__ int   s_wtot[16];      // per-wave counts -> exclusive offsets
  __shared__ int   s_mode, s_ntrue;

  // ---- phase A: issue this block's hid loads; keep-alive pins them ----
  const int d4 = bx * 4 + j;        // f4 column index [0, 512)
  const int o  = b * MLEN + c * TCH;
  const f4* xp = (const f4*)hid + ((size_t)o * DMODEL >> 2) + d4;
  f4 xr[TCH];
  #pragma unroll
  for (int t = 0; t < TCH; ++t) xr[t] = xp[(size_t)t * (DMODEL / 4)];
  #pragma unroll
  for (int t = 0; t < TCH; ++t) asm volatile("" : "+v"(xr[t]));

  // ---- phase B: redundant prep, all 1024 threads (4 positions each) ----
  if (tid == 0) {
    unsigned w0 = ((const unsigned*)bmask_raw)[0];
    s_mode = (w0 <= 1u) ? 1 : 0;    // 1: int32 per element, 0: uint8
  }
  __syncthreads();
  const int mode = s_mode;
  const unsigned char* bmask_u8 = (const unsigned char*)bmask_raw;

  const int PER  = LFULL / 1024;    // 4 positions per thread
  const int base = tid * PER;

  int cnt = 0;
  {
    #pragma unroll
    for (int i = 0; i < PER; ++i) {
      const int L = base + i;
      const int v = mode ? (bmask_raw[b * LFULL + L] != 0)
                         : (bmask_u8[b * LFULL + L] != 0);
      cnt += v;
    }
  }

  // two-level exclusive prefix over 1024 per-thread counts
  const int lane = tid & 63, wv = tid >> 6;
  int incl = cnt;
  #pragma unroll
  for (int off = 1; off < 64; off <<= 1) {
    const int v = __shfl_up(incl, off, 64);
    if (lane >= off) incl += v;
  }
  if (lane == 63) s_wtot[wv] = incl;     // wave totals
  __syncthreads();
  if (tid == 0) {
    int run = 0;
    #pragma unroll
    for (int w = 0; w < 16; ++w) { const int t = s_wtot[w]; s_wtot[w] = run; run += t; }
    s_ntrue = run;
  }
  __syncthreads();
  const int excl  = (incl - cnt) + s_wtot[wv];
  const int ntrue = s_ntrue;

  // fill sel: boundary positions (rank) then non-boundary (ntrue + false-rank)
  {
    int trun = excl;
    #pragma unroll
    for (int i = 0; i < PER; ++i) {
      const int L = base + i;
      const int v = mode ? (bmask_raw[b * LFULL + L] != 0)
                         : (bmask_u8[b * LFULL + L] != 0);
      if (v) {
        if (trun < MLEN) s_sel[trun] = L;
        ++trun;
      } else {
        const int f = L - trun;          // falses strictly before L
        const int slot = ntrue + f;
        if (slot < MLEN) s_sel[slot] = L;
      }
    }
  }
  __syncthreads();

  // own-chunk params to registers (4 j-lanes compute redundantly);
  // bit-identical formulas: w = p/dt, e = 1-p, cde = running product.
  float w[TCH], e[TCH], cd[TCH];
  {
    float run = 1.0f;
    #pragma unroll
    for (int t = 0; t < TCH; ++t) {
      const int L = s_sel[c * TCH + t];
      float p = bprob[((size_t)b * LFULL + L) * 2 + 1];
      p = fminf(fmaxf(p, CLIP_EPS), 1.0f - CLIP_EPS);
      const float dt = -log1pf(-p);      // log(1/(1-p))
      w[t] = p / dt;
      e[t] = 1.0f - p;                   // exp(-dt) exactly
      run *= e[t];
      cd[t] = run;
    }
  }

  // ---- phase C: local chunk scan in registers; publish S, P ----
  f4 st = {0.f, 0.f, 0.f, 0.f};
  #pragma unroll
  for (int t = 0; t < TCH; ++t) {
    const f4 x = xr[t];
    st.x = fmaf(e[t], st.x, w[t] * x.x);
    st.y = fmaf(e[t], st.y, w[t] * x.y);
    st.z = fmaf(e[t], st.z, w[t] * x.z);
    st.w = fmaf(e[t], st.w, w[t] * x.w);
    xr[t] = st;                          // running local state at position t
  }
  s_S[c][j] = st;
  if (j == 0) s_P[c] = cd[TCH - 1];      // chunk product
  __syncthreads();

  // ---- phase D: Hillis-Steele over 256 chunks (identical to k25 math) ----
  for (int dstep = 1; dstep < CCH; dstep <<= 1) {
    const float pc = s_P[c];
    float pd = 1.0f;
    f4 sd = {0.f, 0.f, 0.f, 0.f};
    if (c >= dstep) { pd = s_P[c - dstep]; sd = s_S[c - dstep][j]; }
    __syncthreads();
    if (c >= dstep) {
      f4 cur = s_S[c][j];
      cur.x = fmaf(pc, sd.x, cur.x);
      cur.y = fmaf(pc, sd.y, cur.y);
      cur.z = fmaf(pc, sd.z, cur.z);
      cur.w = fmaf(pc, sd.w, cur.w);
      s_S[c][j] = cur;
      if (j == 0) s_P[c] = pc * pd;
    }
    __syncthreads();
  }

  // exclusive shift: carry-in for chunk c is inclusive scan at c-1
  f4 H = {0.f, 0.f, 0.f, 0.f};
  if (c > 0) H = s_S[c - 1][j];

  // ---- phase E: y = xr + cde*H, PLAIN stores to rows [ls, le) ----
  const int nb = (ntrue < MLEN) ? ntrue : MLEN;
  f4* op = (f4*)out + ((size_t)b * LFULL * DMODEL >> 2) + d4;
  #pragma unroll
  for (int t = 0; t < TCH; ++t) {
    const int g = c * TCH + t;           // global selected index [0, MLEN)
    int ls, le;
    if (nb == 0) {
      ls = (g == 0) ? 0 : LFULL;
      le = (g == 0) ? LFULL : LFULL;
    } else if (g < nb) {
      ls = (g == 0) ? 0 : s_sel[g];
      le = (g == nb - 1) ? LFULL : s_sel[g + 1];
    } else {
      ls = LFULL; le = LFULL;            // empty
    }
    f4 y;
    y.x = fmaf(cd[t], H.x, xr[t].x);
    y.y = fmaf(cd[t], H.y, xr[t].y);
    y.z = fmaf(cd[t], H.z, xr[t].z);
    y.w = fmaf(cd[t], H.w, xr[t].w);
    for (int L = ls; L < le; ++L) {
      op[(size_t)L * (DMODEL / 4)] = y;  // plain cached store
    }
  }
}

// ---------------------------------------------------------------------------
extern "C" void kernel_launch(void* const* d_in, const int* in_sizes, int n_in,
                              void* d_out, int out_size, void* d_ws, size_t ws_size,
                              hipStream_t stream) {
  const float* hid   = (const float*)d_in[0];   // (2, 2048, 2048) fp32
  const int*   bmask = (const int*)d_in[1];     // (2, 4096) bool (layout sniffed)
  const float* bprob = (const float*)d_in[2];   // (2, 4096, 2) fp32
  float*       out   = (float*)d_out;           // (2, 4096, 2048) fp32
  (void)d_ws; (void)ws_size;

  mega<<<dim3(DMODEL / 16, BSZ), dim3(1024), 0, stream>>>(hid, bmask, bprob, out);
}